// Round 1
// baseline (1900.888 us; speedup 1.0000x reference)
//
#include <hip/hip_runtime.h>
#include <stdint.h>

// out[b,d,n] = sum_m adj[b,n,m] * x[b,d,m]
// GEMM: C[m,n] = sum_k A[m,k] * B[n,k], A = x (3072x8192), B = adj (8192x8192), per batch.
#define GM 3072
#define GN 8192
#define GK 8192
#define GB 2

#define BM 128
#define BN 128
#define BK 64

typedef __bf16 bf16x8 __attribute__((ext_vector_type(8)));
typedef float f32x4 __attribute__((ext_vector_type(4)));
typedef unsigned short u16x8 __attribute__((ext_vector_type(8)));

__device__ __forceinline__ unsigned short f2bf(float f) {
  union { float f; unsigned u; } v; v.f = f;
  return (unsigned short)((v.u + 0x7FFFu + ((v.u >> 16) & 1u)) >> 16);  // RTNE
}

__device__ __forceinline__ void gl2lds16(const void* g, void* l) {
  // async 16B/lane global->LDS; LDS dest = wave-uniform base + lane*16
  __builtin_amdgcn_global_load_lds(
      (const __attribute__((address_space(1))) unsigned int*)g,
      (__attribute__((address_space(3))) unsigned int*)l, 16, 0, 0);
}

__global__ void cvt_f32_bf16(const float4* __restrict__ in,
                             ushort4* __restrict__ out, int n4) {
  int i = blockIdx.x * blockDim.x + threadIdx.x;
  int stride = gridDim.x * blockDim.x;
  for (; i < n4; i += stride) {
    float4 f = in[i];
    ushort4 o;
    o.x = f2bf(f.x); o.y = f2bf(f.y); o.z = f2bf(f.z); o.w = f2bf(f.w);
    out[i] = o;
  }
}

// LDS layout: tile[row][k], row-major, rows of BK=64 bf16 = 128 B = 8 segments
// of 16 B. Segment seg of row is stored at slot (seg ^ (row&7)) — keeps the
// wave's global_load_lds destinations lane-contiguous (we permute the SOURCE
// addresses instead) and spreads each quad's ds_read_b128 over all 32 banks.
template <bool ASYNC>
__global__ __launch_bounds__(256) void gcn_gemm(const void* __restrict__ Av,
                                                const void* __restrict__ Bv,
                                                float* __restrict__ C) {
  __shared__ __attribute__((aligned(16))) uint16_t sA[BM * BK];
  __shared__ __attribute__((aligned(16))) uint16_t sB[BN * BK];

  const int tid = threadIdx.x;
  const int lane = tid & 63;
  const int w = tid >> 6;       // 4 waves, 2x2 grid of 64x64 sub-tiles
  const int wm = w >> 1;
  const int wn = w & 1;
  const int t16 = lane & 15;
  const int q = lane >> 4;

  const int b = blockIdx.z;
  const int m0 = blockIdx.y * BM;
  const int n0 = blockIdx.x * BN;

  f32x4 acc[4][4] = {};
  const int swz = t16 & 7;  // fragment row & 7 (i*16 doesn't affect low 3 bits)

  for (int k0 = 0; k0 < GK; k0 += BK) {
    if (ASYNC) {
      const uint16_t* Ab = (const uint16_t*)Av + (size_t)b * GM * GK + (size_t)m0 * GK + k0;
      const uint16_t* Bb = (const uint16_t*)Bv + (size_t)b * GN * GK + (size_t)n0 * GK + k0;
#pragma unroll
      for (int i = 0; i < 4; i++) {
        const int t = i * 256 + tid;       // 16B chunk id: this lane's LDS slot
        const int row = t >> 3;            // 8 chunks per 128B row
        const int segg = (t & 7) ^ (row & 7);  // swizzled source segment
        gl2lds16(Ab + (size_t)row * GK + segg * 8,
                 (char*)sA + (size_t)(i * 256 + w * 64) * 16);
        gl2lds16(Bb + (size_t)row * GK + segg * 8,
                 (char*)sB + (size_t)(i * 256 + w * 64) * 16);
      }
    } else {
      const float* Af = (const float*)Av + (size_t)b * GM * GK + (size_t)m0 * GK + k0;
      const float* Bf = (const float*)Bv + (size_t)b * GN * GK + (size_t)n0 * GK + k0;
#pragma unroll
      for (int i = 0; i < 4; i++) {
        const int t = i * 256 + tid;
        const int row = t >> 3;
        const int segg = (t & 7) ^ (row & 7);
        {
          const float* p = Af + (size_t)row * GK + segg * 8;
          float4 f0 = *(const float4*)p;
          float4 f1 = *(const float4*)(p + 4);
          u16x8 vv = {f2bf(f0.x), f2bf(f0.y), f2bf(f0.z), f2bf(f0.w),
                      f2bf(f1.x), f2bf(f1.y), f2bf(f1.z), f2bf(f1.w)};
          *(u16x8*)((char*)sA + (size_t)t * 16) = vv;
        }
        {
          const float* p = Bf + (size_t)row * GK + segg * 8;
          float4 f0 = *(const float4*)p;
          float4 f1 = *(const float4*)(p + 4);
          u16x8 vv = {f2bf(f0.x), f2bf(f0.y), f2bf(f0.z), f2bf(f0.w),
                      f2bf(f1.x), f2bf(f1.y), f2bf(f1.z), f2bf(f1.w)};
          *(u16x8*)((char*)sB + (size_t)t * 16) = vv;
        }
      }
    }
    __syncthreads();  // implies vmcnt(0)+lgkmcnt(0) drain before barrier

#pragma unroll
    for (int s = 0; s < BK / 32; s++) {
      bf16x8 af[4], bfr[4];
#pragma unroll
      for (int i = 0; i < 4; i++) {
        const int r = wm * 64 + i * 16 + t16;  // A row (m), frag k = s*32+q*8..+7
        af[i] = *(const bf16x8*)((const char*)sA + r * (BK * 2) +
                                 (((s * 4 + q) ^ swz) * 16));
      }
#pragma unroll
      for (int j = 0; j < 4; j++) {
        const int r = wn * 64 + j * 16 + t16;  // B row (n)
        bfr[j] = *(const bf16x8*)((const char*)sB + r * (BK * 2) +
                                  (((s * 4 + q) ^ swz) * 16));
      }
#pragma unroll
      for (int i = 0; i < 4; i++)
#pragma unroll
        for (int j = 0; j < 4; j++)
          acc[i][j] = __builtin_amdgcn_mfma_f32_16x16x32_bf16(af[i], bfr[j],
                                                              acc[i][j], 0, 0, 0);
    }
    __syncthreads();
  }

  // C/D layout (m89-verified): col = lane&15 (n), row = (lane>>4)*4 + reg (m)
  float* Cp = C + (size_t)b * GM * GN;
#pragma unroll
  for (int i = 0; i < 4; i++) {
    const int rowb = m0 + wm * 64 + i * 16 + q * 4;
#pragma unroll
    for (int j = 0; j < 4; j++) {
      const int col = n0 + wn * 64 + j * 16 + t16;
#pragma unroll
      for (int r = 0; r < 4; r++)
        Cp[(size_t)(rowb + r) * GN + col] = acc[i][j][r];
    }
  }
}

extern "C" void kernel_launch(void* const* d_in, const int* in_sizes, int n_in,
                              void* d_out, int out_size, void* d_ws, size_t ws_size,
                              hipStream_t stream) {
  const float* x = (const float*)d_in[0];    // (B, D, N) = (2, 3072, 8192)
  const float* adj = (const float*)d_in[1];  // (B, N, N) = (2, 8192, 8192)
  float* out = (float*)d_out;                // (B, D, N)

  const size_t xe = (size_t)GB * GM * GK;  // 50,331,648
  const size_t ae = (size_t)GB * GN * GK;  // 134,217,728
  const size_t need = (xe + ae) * sizeof(uint16_t);  // ~352 MiB

  dim3 grid(GN / BN, GM / BM, GB);  // (64, 24, 2)

  if (ws_size >= need) {
    uint16_t* xb = (uint16_t*)d_ws;
    uint16_t* ab = xb + xe;
    cvt_f32_bf16<<<4096, 256, 0, stream>>>((const float4*)x, (ushort4*)xb, (int)(xe / 4));
    cvt_f32_bf16<<<4096, 256, 0, stream>>>((const float4*)adj, (ushort4*)ab, (int)(ae / 4));
    gcn_gemm<true><<<grid, 256, 0, stream>>>(xb, ab, out);
  } else {
    // ws too small for bf16 copies: stage fp32->bf16 through registers
    gcn_gemm<false><<<grid, 256, 0, stream>>>(x, adj, out);
  }
}